// Round 1
// baseline (1755.488 us; speedup 1.0000x reference)
//
#include <hip/hip_runtime.h>

#define N0c 262144
#define INc 128
#define Hc  32
#define N1c 131072
#define N2c 65536
#define E0c 2097152
#define E1c 1048576

__device__ __forceinline__ void fma4(float4& a, float s, const float4 w) {
    a.x = fmaf(s, w.x, a.x);
    a.y = fmaf(s, w.y, a.y);
    a.z = fmaf(s, w.z, a.z);
    a.w = fmaf(s, w.w, a.w);
}

// ---------------- layer-0 linear: y = x @ wl^T (all N0 rows), z = x @ wr^T (rows < N1) ----
// 64 rows/block, 128 threads, each thread 4 rows x 4 cols. K=128.
// LDS exactly 64 KB: xs 32KB + wls 16KB + wrs 16KB, chunk-swizzled for conflict-free b128.
__global__ __launch_bounds__(128) void lin0_kernel(
    const float* __restrict__ x, const float* __restrict__ wl,
    const float* __restrict__ wr, float* __restrict__ y, float* __restrict__ z)
{
    __shared__ float xs[64 * 128];
    __shared__ float wls[128 * 32];
    __shared__ float wrs[128 * 32];
    const int t = threadIdx.x;
    const long rowBase = (long)blockIdx.x * 64;
    const bool doZ = rowBase < N1c;

    // stage weights [32][128] -> [k][j], swizzle j-chunk by (j>>2 + k)&7
#pragma unroll
    for (int i = 0; i < 32; ++i) {
        int idx = t + 128 * i;          // = j*128 + k
        int j = idx >> 7, k = idx & 127;
        int dst = k * 32 + 4 * (((j >> 2) + k) & 7) + (j & 3);
        wls[dst] = wl[idx];
        if (doZ) wrs[dst] = wr[idx];
    }
    // stage x tile row-major, float4-chunk rotated by row>>2
#pragma unroll
    for (int i = 0; i < 16; ++i) {
        int idx = t + 128 * i;          // float4 index, 0..2047
        int row = idx >> 5, k4 = idx & 31;
        float4 v = ((const float4*)x)[rowBase * 32 + idx];
        ((float4*)xs)[row * 32 + ((k4 + (row >> 2)) & 31)] = v;
    }
    __syncthreads();

    const int cg = t & 7;       // col group (4 cols)
    const int rg = t >> 3;      // row group (4 rows)
    const float4* xs4  = (const float4*)xs;
    const float4* wls4 = (const float4*)wls;
    const float4* wrs4 = (const float4*)wrs;

    float4 accY[4], accZ[4];
#pragma unroll
    for (int i = 0; i < 4; ++i) {
        accY[i] = make_float4(0.f, 0.f, 0.f, 0.f);
        accZ[i] = make_float4(0.f, 0.f, 0.f, 0.f);
    }

#pragma unroll 4
    for (int k4 = 0; k4 < 32; ++k4) {
        float4 xv[4];
#pragma unroll
        for (int i = 0; i < 4; ++i)
            xv[i] = xs4[(4 * rg + i) * 32 + ((k4 + rg) & 31)];
        const int kb = 4 * k4;
        float4 w0 = wls4[(kb + 0) * 8 + ((cg + kb + 0) & 7)];
        float4 w1 = wls4[(kb + 1) * 8 + ((cg + kb + 1) & 7)];
        float4 w2 = wls4[(kb + 2) * 8 + ((cg + kb + 2) & 7)];
        float4 w3 = wls4[(kb + 3) * 8 + ((cg + kb + 3) & 7)];
#pragma unroll
        for (int i = 0; i < 4; ++i) {
            fma4(accY[i], xv[i].x, w0);
            fma4(accY[i], xv[i].y, w1);
            fma4(accY[i], xv[i].z, w2);
            fma4(accY[i], xv[i].w, w3);
        }
        if (doZ) {
            float4 u0 = wrs4[(kb + 0) * 8 + ((cg + kb + 0) & 7)];
            float4 u1 = wrs4[(kb + 1) * 8 + ((cg + kb + 1) & 7)];
            float4 u2 = wrs4[(kb + 2) * 8 + ((cg + kb + 2) & 7)];
            float4 u3 = wrs4[(kb + 3) * 8 + ((cg + kb + 3) & 7)];
#pragma unroll
            for (int i = 0; i < 4; ++i) {
                fma4(accZ[i], xv[i].x, u0);
                fma4(accZ[i], xv[i].y, u1);
                fma4(accZ[i], xv[i].z, u2);
                fma4(accZ[i], xv[i].w, u3);
            }
        }
    }
#pragma unroll
    for (int i = 0; i < 4; ++i) {
        long r = rowBase + 4 * rg + i;
        ((float4*)y)[r * 8 + cg] = accY[i];
        if (doZ) ((float4*)z)[r * 8 + cg] = accZ[i];
    }
}

// ---------------- layer-1 linear: same structure, K=32 ----------------
__global__ __launch_bounds__(128) void lin1_kernel(
    const float* __restrict__ h, const float* __restrict__ wl,
    const float* __restrict__ wr, float* __restrict__ y, float* __restrict__ z)
{
    __shared__ float xs[64 * 32];
    __shared__ float wls[32 * 32];
    __shared__ float wrs[32 * 32];
    const int t = threadIdx.x;
    const long rowBase = (long)blockIdx.x * 64;
    const bool doZ = rowBase < N2c;

#pragma unroll
    for (int i = 0; i < 8; ++i) {
        int idx = t + 128 * i;          // = j*32 + k
        int j = idx >> 5, k = idx & 31;
        int dst = k * 32 + 4 * (((j >> 2) + k) & 7) + (j & 3);
        wls[dst] = wl[idx];
        if (doZ) wrs[dst] = wr[idx];
    }
#pragma unroll
    for (int i = 0; i < 4; ++i) {
        int idx = t + 128 * i;          // float4 idx 0..511
        int row = idx >> 3, k4 = idx & 7;
        float4 v = ((const float4*)h)[rowBase * 8 + idx];
        ((float4*)xs)[row * 8 + ((k4 + (row >> 2)) & 7)] = v;
    }
    __syncthreads();

    const int cg = t & 7;
    const int rg = t >> 3;
    const float4* xs4  = (const float4*)xs;
    const float4* wls4 = (const float4*)wls;
    const float4* wrs4 = (const float4*)wrs;

    float4 accY[4], accZ[4];
#pragma unroll
    for (int i = 0; i < 4; ++i) {
        accY[i] = make_float4(0.f, 0.f, 0.f, 0.f);
        accZ[i] = make_float4(0.f, 0.f, 0.f, 0.f);
    }

#pragma unroll
    for (int k4 = 0; k4 < 8; ++k4) {
        float4 xv[4];
#pragma unroll
        for (int i = 0; i < 4; ++i)
            xv[i] = xs4[(4 * rg + i) * 8 + ((k4 + rg) & 7)];
        const int kb = 4 * k4;
        float4 w0 = wls4[(kb + 0) * 8 + ((cg + kb + 0) & 7)];
        float4 w1 = wls4[(kb + 1) * 8 + ((cg + kb + 1) & 7)];
        float4 w2 = wls4[(kb + 2) * 8 + ((cg + kb + 2) & 7)];
        float4 w3 = wls4[(kb + 3) * 8 + ((cg + kb + 3) & 7)];
#pragma unroll
        for (int i = 0; i < 4; ++i) {
            fma4(accY[i], xv[i].x, w0);
            fma4(accY[i], xv[i].y, w1);
            fma4(accY[i], xv[i].z, w2);
            fma4(accY[i], xv[i].w, w3);
        }
        if (doZ) {
            float4 u0 = wrs4[(kb + 0) * 8 + ((cg + kb + 0) & 7)];
            float4 u1 = wrs4[(kb + 1) * 8 + ((cg + kb + 1) & 7)];
            float4 u2 = wrs4[(kb + 2) * 8 + ((cg + kb + 2) & 7)];
            float4 u3 = wrs4[(kb + 3) * 8 + ((cg + kb + 3) & 7)];
#pragma unroll
            for (int i = 0; i < 4; ++i) {
                fma4(accZ[i], xv[i].x, u0);
                fma4(accZ[i], xv[i].y, u1);
                fma4(accZ[i], xv[i].z, u2);
                fma4(accZ[i], xv[i].w, u3);
            }
        }
    }
#pragma unroll
    for (int i = 0; i < 4; ++i) {
        long r = rowBase + 4 * rg + i;
        ((float4*)y)[r * 8 + cg] = accY[i];
        if (doZ) ((float4*)z)[r * 8 + cg] = accZ[i];
    }
}

// ---------------- edge scatter: agg[tgt] += y[src], cnt[tgt] += 1 ----------------
// 8 threads per edge, float4 gather + 4 f32 atomics each.
__global__ __launch_bounds__(256) void scatter_kernel(
    const float* __restrict__ yv, const int* __restrict__ src,
    const int* __restrict__ tgt, float* __restrict__ agg,
    int* __restrict__ cnt, int nE)
{
    int t = blockIdx.x * 256 + threadIdx.x;
    int e = t >> 3, part = t & 7;
    if (e >= nE) return;
    int s = src[e];
    int d = tgt[e];
    float4 v = ((const float4*)yv)[(long)s * 8 + part];
    float* a = agg + (long)d * 32 + part * 4;
    atomicAdd(a + 0, v.x);
    atomicAdd(a + 1, v.y);
    atomicAdd(a + 2, v.z);
    atomicAdd(a + 3, v.w);
    if (part == 0) atomicAdd(cnt + d, 1);
}

// ---------------- epilogue: mean + bias + root, L2-normalize row, optional relu ----
__global__ __launch_bounds__(256) void finish_kernel(
    const float* __restrict__ agg, const int* __restrict__ cnt,
    const float* __restrict__ z, const float* __restrict__ b,
    float* __restrict__ out, int n, int doRelu)
{
    int t = blockIdx.x * 256 + threadIdx.x;
    int row = t >> 5, j = t & 31;
    if (row >= n) return;
    float c = fmaxf((float)cnt[row], 1.0f);
    float v = agg[t] / c + b[j] + z[t];
    float ss = v * v;
#pragma unroll
    for (int m = 1; m < 32; m <<= 1)
        ss += __shfl_xor(ss, m);
    float nrm = fmaxf(sqrtf(ss), 1e-12f);
    float o = v / nrm;
    if (doRelu) o = fmaxf(o, 0.f);
    out[t] = o;
}

extern "C" void kernel_launch(void* const* d_in, const int* in_sizes, int n_in,
                              void* d_out, int out_size, void* d_ws, size_t ws_size,
                              hipStream_t stream) {
    const float* x   = (const float*)d_in[0];
    const int* src0  = (const int*)d_in[1];
    const int* tgt0  = (const int*)d_in[2];
    const int* src1  = (const int*)d_in[3];
    const int* tgt1  = (const int*)d_in[4];
    const float* wl0 = (const float*)d_in[5];
    const float* bl0 = (const float*)d_in[6];
    const float* wr0 = (const float*)d_in[7];
    const float* wl1 = (const float*)d_in[8];
    const float* bl1 = (const float*)d_in[9];
    const float* wr1 = (const float*)d_in[10];

    char* W = (char*)d_ws;
    // region A (32 MB): y0, later y1(16MB)+z1(8MB)
    float* y0   = (float*)(W + 0);
    float* y1   = (float*)(W + 0);
    float* z1   = (float*)(W + 16777216);
    // region B (16 MB): z0, later agg1(8MB)+cnt1(0.25MB)
    float* z0   = (float*)(W + 33554432);
    float* agg1 = (float*)(W + 33554432);
    int*   cnt1 = (int*)  (W + 41943040);
    // region C: agg0 (16MB) + cnt0 (0.5MB), contiguous
    float* agg0 = (float*)(W + 50331648);
    int*   cnt0 = (int*)  (W + 67108864);
    // region D: h (16MB)
    float* h    = (float*)(W + 67633152);

    // layer 0
    hipMemsetAsync(agg0, 0, 16777216 + 524288, stream);       // agg0 + cnt0
    lin0_kernel<<<N0c / 64, 128, 0, stream>>>(x, wl0, wr0, y0, z0);
    scatter_kernel<<<(E0c * 8) / 256, 256, 0, stream>>>(y0, src0, tgt0, agg0, cnt0, E0c);
    finish_kernel<<<(N1c * 32) / 256, 256, 0, stream>>>(agg0, cnt0, z0, bl0, h, N1c, 1);

    // layer 1 (z0 dead now; reuse its region for agg1/cnt1)
    hipMemsetAsync(agg1, 0, 8388608 + 262144, stream);        // agg1 + cnt1
    lin1_kernel<<<N1c / 64, 128, 0, stream>>>(h, wl1, wr1, y1, z1);
    scatter_kernel<<<(E1c * 8) / 256, 256, 0, stream>>>(y1, src1, tgt1, agg1, cnt1, E1c);
    finish_kernel<<<(N2c * 32) / 256, 256, 0, stream>>>(agg1, cnt1, z1, bl1, (float*)d_out, N2c, 0);
}

// Round 2
// 778.297 us; speedup vs baseline: 2.2556x; 2.2556x over previous
//
#include <hip/hip_runtime.h>

#define N0c 262144
#define INc 128
#define Hc  32
#define N1c 131072
#define N2c 65536
#define E0c 2097152
#define E1c 1048576

__device__ __forceinline__ void fma4(float4& a, float s, const float4 w) {
    a.x = fmaf(s, w.x, a.x);
    a.y = fmaf(s, w.y, a.y);
    a.z = fmaf(s, w.z, a.z);
    a.w = fmaf(s, w.w, a.w);
}

// ---------------- layer-0 linear: y = x @ wl^T (all N0 rows), z = x @ wr^T (rows < N1) ----
__global__ __launch_bounds__(128) void lin0_kernel(
    const float* __restrict__ x, const float* __restrict__ wl,
    const float* __restrict__ wr, float* __restrict__ y, float* __restrict__ z)
{
    __shared__ float xs[64 * 128];
    __shared__ float wls[128 * 32];
    __shared__ float wrs[128 * 32];
    const int t = threadIdx.x;
    const long rowBase = (long)blockIdx.x * 64;
    const bool doZ = rowBase < N1c;

#pragma unroll
    for (int i = 0; i < 32; ++i) {
        int idx = t + 128 * i;          // = j*128 + k
        int j = idx >> 7, k = idx & 127;
        int dst = k * 32 + 4 * (((j >> 2) + k) & 7) + (j & 3);
        wls[dst] = wl[idx];
        if (doZ) wrs[dst] = wr[idx];
    }
#pragma unroll
    for (int i = 0; i < 16; ++i) {
        int idx = t + 128 * i;          // float4 index, 0..2047
        int row = idx >> 5, k4 = idx & 31;
        float4 v = ((const float4*)x)[rowBase * 32 + idx];
        ((float4*)xs)[row * 32 + ((k4 + (row >> 2)) & 31)] = v;
    }
    __syncthreads();

    const int cg = t & 7;       // col group (4 cols)
    const int rg = t >> 3;      // row group (4 rows)
    const float4* xs4  = (const float4*)xs;
    const float4* wls4 = (const float4*)wls;
    const float4* wrs4 = (const float4*)wrs;

    float4 accY[4], accZ[4];
#pragma unroll
    for (int i = 0; i < 4; ++i) {
        accY[i] = make_float4(0.f, 0.f, 0.f, 0.f);
        accZ[i] = make_float4(0.f, 0.f, 0.f, 0.f);
    }

#pragma unroll 4
    for (int k4 = 0; k4 < 32; ++k4) {
        float4 xv[4];
#pragma unroll
        for (int i = 0; i < 4; ++i)
            xv[i] = xs4[(4 * rg + i) * 32 + ((k4 + rg) & 31)];
        const int kb = 4 * k4;
        float4 w0 = wls4[(kb + 0) * 8 + ((cg + kb + 0) & 7)];
        float4 w1 = wls4[(kb + 1) * 8 + ((cg + kb + 1) & 7)];
        float4 w2 = wls4[(kb + 2) * 8 + ((cg + kb + 2) & 7)];
        float4 w3 = wls4[(kb + 3) * 8 + ((cg + kb + 3) & 7)];
#pragma unroll
        for (int i = 0; i < 4; ++i) {
            fma4(accY[i], xv[i].x, w0);
            fma4(accY[i], xv[i].y, w1);
            fma4(accY[i], xv[i].z, w2);
            fma4(accY[i], xv[i].w, w3);
        }
        if (doZ) {
            float4 u0 = wrs4[(kb + 0) * 8 + ((cg + kb + 0) & 7)];
            float4 u1 = wrs4[(kb + 1) * 8 + ((cg + kb + 1) & 7)];
            float4 u2 = wrs4[(kb + 2) * 8 + ((cg + kb + 2) & 7)];
            float4 u3 = wrs4[(kb + 3) * 8 + ((cg + kb + 3) & 7)];
#pragma unroll
            for (int i = 0; i < 4; ++i) {
                fma4(accZ[i], xv[i].x, u0);
                fma4(accZ[i], xv[i].y, u1);
                fma4(accZ[i], xv[i].z, u2);
                fma4(accZ[i], xv[i].w, u3);
            }
        }
    }
#pragma unroll
    for (int i = 0; i < 4; ++i) {
        long r = rowBase + 4 * rg + i;
        ((float4*)y)[r * 8 + cg] = accY[i];
        if (doZ) ((float4*)z)[r * 8 + cg] = accZ[i];
    }
}

// ---------------- layer-1 linear: same structure, K=32 ----------------
__global__ __launch_bounds__(128) void lin1_kernel(
    const float* __restrict__ h, const float* __restrict__ wl,
    const float* __restrict__ wr, float* __restrict__ y, float* __restrict__ z)
{
    __shared__ float xs[64 * 32];
    __shared__ float wls[32 * 32];
    __shared__ float wrs[32 * 32];
    const int t = threadIdx.x;
    const long rowBase = (long)blockIdx.x * 64;
    const bool doZ = rowBase < N2c;

#pragma unroll
    for (int i = 0; i < 8; ++i) {
        int idx = t + 128 * i;          // = j*32 + k
        int j = idx >> 5, k = idx & 31;
        int dst = k * 32 + 4 * (((j >> 2) + k) & 7) + (j & 3);
        wls[dst] = wl[idx];
        if (doZ) wrs[dst] = wr[idx];
    }
#pragma unroll
    for (int i = 0; i < 4; ++i) {
        int idx = t + 128 * i;          // float4 idx 0..511
        int row = idx >> 3, k4 = idx & 7;
        float4 v = ((const float4*)h)[rowBase * 8 + idx];
        ((float4*)xs)[row * 8 + ((k4 + (row >> 2)) & 7)] = v;
    }
    __syncthreads();

    const int cg = t & 7;
    const int rg = t >> 3;
    const float4* xs4  = (const float4*)xs;
    const float4* wls4 = (const float4*)wls;
    const float4* wrs4 = (const float4*)wrs;

    float4 accY[4], accZ[4];
#pragma unroll
    for (int i = 0; i < 4; ++i) {
        accY[i] = make_float4(0.f, 0.f, 0.f, 0.f);
        accZ[i] = make_float4(0.f, 0.f, 0.f, 0.f);
    }

#pragma unroll
    for (int k4 = 0; k4 < 8; ++k4) {
        float4 xv[4];
#pragma unroll
        for (int i = 0; i < 4; ++i)
            xv[i] = xs4[(4 * rg + i) * 8 + ((k4 + rg) & 7)];
        const int kb = 4 * k4;
        float4 w0 = wls4[(kb + 0) * 8 + ((cg + kb + 0) & 7)];
        float4 w1 = wls4[(kb + 1) * 8 + ((cg + kb + 1) & 7)];
        float4 w2 = wls4[(kb + 2) * 8 + ((cg + kb + 2) & 7)];
        float4 w3 = wls4[(kb + 3) * 8 + ((cg + kb + 3) & 7)];
#pragma unroll
        for (int i = 0; i < 4; ++i) {
            fma4(accY[i], xv[i].x, w0);
            fma4(accY[i], xv[i].y, w1);
            fma4(accY[i], xv[i].z, w2);
            fma4(accY[i], xv[i].w, w3);
        }
        if (doZ) {
            float4 u0 = wrs4[(kb + 0) * 8 + ((cg + kb + 0) & 7)];
            float4 u1 = wrs4[(kb + 1) * 8 + ((cg + kb + 1) & 7)];
            float4 u2 = wrs4[(kb + 2) * 8 + ((cg + kb + 2) & 7)];
            float4 u3 = wrs4[(kb + 3) * 8 + ((cg + kb + 3) & 7)];
#pragma unroll
            for (int i = 0; i < 4; ++i) {
                fma4(accZ[i], xv[i].x, u0);
                fma4(accZ[i], xv[i].y, u1);
                fma4(accZ[i], xv[i].z, u2);
                fma4(accZ[i], xv[i].w, u3);
            }
        }
    }
#pragma unroll
    for (int i = 0; i < 4; ++i) {
        long r = rowBase + 4 * rg + i;
        ((float4*)y)[r * 8 + cg] = accY[i];
        if (doZ) ((float4*)z)[r * 8 + cg] = accZ[i];
    }
}

// ---------------- CSR build: histogram ----------------
__global__ __launch_bounds__(256) void hist_kernel(
    const int* __restrict__ tgt, int* __restrict__ cnt, int nE)
{
    int e = blockIdx.x * 256 + threadIdx.x;
    if (e < nE) atomicAdd(&cnt[tgt[e]], 1);
}

// ---------------- CSR build: 2-level exclusive scan ----------------
// scanA: each block scans 512 counts (2/thread), writes exclusive results + block sum
__global__ __launch_bounds__(256) void scanA_kernel(
    const int* __restrict__ cnt, int* __restrict__ cursor, int* __restrict__ bsum)
{
    __shared__ int s[256];
    int t = threadIdx.x;
    int base = blockIdx.x * 512;
    int c0 = cnt[base + 2 * t];
    int c1 = cnt[base + 2 * t + 1];
    int local = c0 + c1;
    s[t] = local;
    __syncthreads();
    int v = local;
#pragma unroll
    for (int off = 1; off < 256; off <<= 1) {
        int u = (t >= off) ? s[t - off] : 0;
        __syncthreads();
        v += u;
        s[t] = v;
        __syncthreads();
    }
    int ex = v - local;
    cursor[base + 2 * t]     = ex;
    cursor[base + 2 * t + 1] = ex + c0;
    if (t == 255) bsum[blockIdx.x] = v;
}

// scanB: single block, exclusive scan of up to 256 block sums
__global__ __launch_bounds__(256) void scanB_kernel(int* __restrict__ bsum, int nb)
{
    __shared__ int s[256];
    int t = threadIdx.x;
    int local = (t < nb) ? bsum[t] : 0;
    s[t] = local;
    __syncthreads();
    int v = local;
#pragma unroll
    for (int off = 1; off < 256; off <<= 1) {
        int u = (t >= off) ? s[t - off] : 0;
        __syncthreads();
        v += u;
        s[t] = v;
        __syncthreads();
    }
    if (t < nb) bsum[t] = v - local;
}

// scanC: add block offsets
__global__ __launch_bounds__(256) void scanC_kernel(
    int* __restrict__ cursor, const int* __restrict__ bsum)
{
    int i = blockIdx.x * 256 + threadIdx.x;
    cursor[i] += bsum[i >> 9];
}

// ---------------- CSR build: reorder edge sources by target ----------------
__global__ __launch_bounds__(256) void reorder_kernel(
    const int* __restrict__ src, const int* __restrict__ tgt,
    int* __restrict__ cursor, int* __restrict__ eidx, int nE)
{
    int e = blockIdx.x * 256 + threadIdx.x;
    if (e < nE) {
        int pos = atomicAdd(&cursor[tgt[e]], 1);
        eidx[pos] = src[e];
    }
}

// ---------------- gather-reduce + fused epilogue ----------------
// 8 lanes per target row (float4 each). After reorder, cursor[row] = row end.
__global__ __launch_bounds__(256) void gather_agg_kernel(
    const float* __restrict__ yv, const int* __restrict__ eidx,
    const int* __restrict__ cnt, const int* __restrict__ cursor,
    const float* __restrict__ z, const float* __restrict__ b,
    float* __restrict__ out, int n, int doRelu)
{
    int t = blockIdx.x * 256 + threadIdx.x;
    int row = t >> 3, part = t & 7;
    if (row >= n) return;
    int c = cnt[row];
    int end = cursor[row];
    int beg = end - c;
    const float4* y4 = (const float4*)yv;
    float4 acc = make_float4(0.f, 0.f, 0.f, 0.f);
    int e = beg;
    for (; e + 1 < end; e += 2) {
        int s0 = eidx[e], s1 = eidx[e + 1];
        float4 v0 = y4[(long)s0 * 8 + part];
        float4 v1 = y4[(long)s1 * 8 + part];
        acc.x += v0.x + v1.x;
        acc.y += v0.y + v1.y;
        acc.z += v0.z + v1.z;
        acc.w += v0.w + v1.w;
    }
    if (e < end) {
        int s0 = eidx[e];
        float4 v0 = y4[(long)s0 * 8 + part];
        acc.x += v0.x; acc.y += v0.y; acc.z += v0.z; acc.w += v0.w;
    }
    float inv = 1.f / fmaxf((float)c, 1.f);
    float4 bb = ((const float4*)b)[part];
    float4 zz = ((const float4*)z)[(long)row * 8 + part];
    float4 v;
    v.x = fmaf(acc.x, inv, bb.x) + zz.x;
    v.y = fmaf(acc.y, inv, bb.y) + zz.y;
    v.z = fmaf(acc.z, inv, bb.z) + zz.z;
    v.w = fmaf(acc.w, inv, bb.w) + zz.w;
    float ss = v.x * v.x + v.y * v.y + v.z * v.z + v.w * v.w;
    ss += __shfl_xor(ss, 1);
    ss += __shfl_xor(ss, 2);
    ss += __shfl_xor(ss, 4);
    float q = 1.f / fmaxf(sqrtf(ss), 1e-12f);
    v.x *= q; v.y *= q; v.z *= q; v.w *= q;
    if (doRelu) {
        v.x = fmaxf(v.x, 0.f); v.y = fmaxf(v.y, 0.f);
        v.z = fmaxf(v.z, 0.f); v.w = fmaxf(v.w, 0.f);
    }
    ((float4*)out)[(long)row * 8 + part] = v;
}

extern "C" void kernel_launch(void* const* d_in, const int* in_sizes, int n_in,
                              void* d_out, int out_size, void* d_ws, size_t ws_size,
                              hipStream_t stream) {
    const float* x   = (const float*)d_in[0];
    const int* src0  = (const int*)d_in[1];
    const int* tgt0  = (const int*)d_in[2];
    const int* src1  = (const int*)d_in[3];
    const int* tgt1  = (const int*)d_in[4];
    const float* wl0 = (const float*)d_in[5];
    const float* bl0 = (const float*)d_in[6];
    const float* wr0 = (const float*)d_in[7];
    const float* wl1 = (const float*)d_in[8];
    const float* bl1 = (const float*)d_in[9];
    const float* wr1 = (const float*)d_in[10];

    char* W = (char*)d_ws;
    // region A [0, 32M): y0; after gather_agg0 reused for layer-1 buffers
    float* y0    = (float*)(W + 0);             // 32 MB
    float* y1    = (float*)(W + 0);             // 16 MB
    float* z1    = (float*)(W + 16777216);      //  8 MB
    int*   eidx1 = (int*)  (W + 25165824);      //  4 MB
    int*   cnt1  = (int*)  (W + 29360128);      // 256 KB
    int*   cur1  = (int*)  (W + 29622272);      // 256 KB
    // region B [32M, 48M): z0
    float* z0    = (float*)(W + 33554432);      // 16 MB
    // region C [48M, 64M): h
    float* h     = (float*)(W + 50331648);      // 16 MB
    // region D [64M, 72M): eidx0
    int*   eidx0 = (int*)  (W + 67108864);      //  8 MB
    // region E [72M, ...): cnt0, cur0, bsum
    int*   cnt0  = (int*)  (W + 75497472);      // 512 KB
    int*   cur0  = (int*)  (W + 76021760);      // 512 KB
    int*   bsum  = (int*)  (W + 76546048);      //  1 KB

    // ---- layer 0 ----
    hipMemsetAsync(cnt0, 0, 524288, stream);
    lin0_kernel<<<N0c / 64, 128, 0, stream>>>(x, wl0, wr0, y0, z0);
    hist_kernel<<<E0c / 256, 256, 0, stream>>>(tgt0, cnt0, E0c);
    scanA_kernel<<<N1c / 512, 256, 0, stream>>>(cnt0, cur0, bsum);
    scanB_kernel<<<1, 256, 0, stream>>>(bsum, N1c / 512);
    scanC_kernel<<<N1c / 256, 256, 0, stream>>>(cur0, bsum);
    reorder_kernel<<<E0c / 256, 256, 0, stream>>>(src0, tgt0, cur0, eidx0, E0c);
    gather_agg_kernel<<<(N1c * 8) / 256, 256, 0, stream>>>(y0, eidx0, cnt0, cur0,
                                                           z0, bl0, h, N1c, 1);

    // ---- layer 1 (y0 dead; region A reused) ----
    hipMemsetAsync(cnt1, 0, 262144, stream);
    hist_kernel<<<E1c / 256, 256, 0, stream>>>(tgt1, cnt1, E1c);
    scanA_kernel<<<N2c / 512, 256, 0, stream>>>(cnt1, cur1, bsum);
    scanB_kernel<<<1, 256, 0, stream>>>(bsum, N2c / 512);
    scanC_kernel<<<N2c / 256, 256, 0, stream>>>(cur1, bsum);
    reorder_kernel<<<E1c / 256, 256, 0, stream>>>(src1, tgt1, cur1, eidx1, E1c);
    lin1_kernel<<<N1c / 64, 128, 0, stream>>>(h, wl1, wr1, y1, z1);
    gather_agg_kernel<<<(N2c * 8) / 256, 256, 0, stream>>>(y1, eidx1, cnt1, cur1,
                                                           z1, bl1, (float*)d_out, N2c, 0);
}

// Round 3
// 639.042 us; speedup vs baseline: 2.7471x; 1.2179x over previous
//
#include <hip/hip_runtime.h>

#define N0c 262144
#define INc 128
#define Hc  32
#define N1c 131072
#define N2c 65536
#define E0c 2097152
#define E1c 1048576

__device__ __forceinline__ void fma4(float4& a, float s, const float4 w) {
    a.x = fmaf(s, w.x, a.x);
    a.y = fmaf(s, w.y, a.y);
    a.z = fmaf(s, w.z, a.z);
    a.w = fmaf(s, w.w, a.w);
}

// ---------------- layer-0 linear: y = x @ wl^T (all N0 rows), z = x @ wr^T (rows < N1) ----
__global__ __launch_bounds__(128) void lin0_kernel(
    const float* __restrict__ x, const float* __restrict__ wl,
    const float* __restrict__ wr, float* __restrict__ y, float* __restrict__ z)
{
    __shared__ float xs[64 * 128];
    __shared__ float wls[128 * 32];
    __shared__ float wrs[128 * 32];
    const int t = threadIdx.x;
    const long rowBase = (long)blockIdx.x * 64;
    const bool doZ = rowBase < N1c;

#pragma unroll
    for (int i = 0; i < 32; ++i) {
        int idx = t + 128 * i;          // = j*128 + k
        int j = idx >> 7, k = idx & 127;
        int dst = k * 32 + 4 * (((j >> 2) + k) & 7) + (j & 3);
        wls[dst] = wl[idx];
        if (doZ) wrs[dst] = wr[idx];
    }
#pragma unroll
    for (int i = 0; i < 16; ++i) {
        int idx = t + 128 * i;          // float4 index, 0..2047
        int row = idx >> 5, k4 = idx & 31;
        float4 v = ((const float4*)x)[rowBase * 32 + idx];
        ((float4*)xs)[row * 32 + ((k4 + (row >> 2)) & 31)] = v;
    }
    __syncthreads();

    const int cg = t & 7;       // col group (4 cols)
    const int rg = t >> 3;      // row group (4 rows)
    const float4* xs4  = (const float4*)xs;
    const float4* wls4 = (const float4*)wls;
    const float4* wrs4 = (const float4*)wrs;

    float4 accY[4], accZ[4];
#pragma unroll
    for (int i = 0; i < 4; ++i) {
        accY[i] = make_float4(0.f, 0.f, 0.f, 0.f);
        accZ[i] = make_float4(0.f, 0.f, 0.f, 0.f);
    }

#pragma unroll 4
    for (int k4 = 0; k4 < 32; ++k4) {
        float4 xv[4];
#pragma unroll
        for (int i = 0; i < 4; ++i)
            xv[i] = xs4[(4 * rg + i) * 32 + ((k4 + rg) & 31)];
        const int kb = 4 * k4;
        float4 w0 = wls4[(kb + 0) * 8 + ((cg + kb + 0) & 7)];
        float4 w1 = wls4[(kb + 1) * 8 + ((cg + kb + 1) & 7)];
        float4 w2 = wls4[(kb + 2) * 8 + ((cg + kb + 2) & 7)];
        float4 w3 = wls4[(kb + 3) * 8 + ((cg + kb + 3) & 7)];
#pragma unroll
        for (int i = 0; i < 4; ++i) {
            fma4(accY[i], xv[i].x, w0);
            fma4(accY[i], xv[i].y, w1);
            fma4(accY[i], xv[i].z, w2);
            fma4(accY[i], xv[i].w, w3);
        }
        if (doZ) {
            float4 u0 = wrs4[(kb + 0) * 8 + ((cg + kb + 0) & 7)];
            float4 u1 = wrs4[(kb + 1) * 8 + ((cg + kb + 1) & 7)];
            float4 u2 = wrs4[(kb + 2) * 8 + ((cg + kb + 2) & 7)];
            float4 u3 = wrs4[(kb + 3) * 8 + ((cg + kb + 3) & 7)];
#pragma unroll
            for (int i = 0; i < 4; ++i) {
                fma4(accZ[i], xv[i].x, u0);
                fma4(accZ[i], xv[i].y, u1);
                fma4(accZ[i], xv[i].z, u2);
                fma4(accZ[i], xv[i].w, u3);
            }
        }
    }
#pragma unroll
    for (int i = 0; i < 4; ++i) {
        long r = rowBase + 4 * rg + i;
        ((float4*)y)[r * 8 + cg] = accY[i];
        if (doZ) ((float4*)z)[r * 8 + cg] = accZ[i];
    }
}

// ---------------- layer-1 linear: same structure, K=32 ----------------
__global__ __launch_bounds__(128) void lin1_kernel(
    const float* __restrict__ h, const float* __restrict__ wl,
    const float* __restrict__ wr, float* __restrict__ y, float* __restrict__ z)
{
    __shared__ float xs[64 * 32];
    __shared__ float wls[32 * 32];
    __shared__ float wrs[32 * 32];
    const int t = threadIdx.x;
    const long rowBase = (long)blockIdx.x * 64;
    const bool doZ = rowBase < N2c;

#pragma unroll
    for (int i = 0; i < 8; ++i) {
        int idx = t + 128 * i;          // = j*32 + k
        int j = idx >> 5, k = idx & 31;
        int dst = k * 32 + 4 * (((j >> 2) + k) & 7) + (j & 3);
        wls[dst] = wl[idx];
        if (doZ) wrs[dst] = wr[idx];
    }
#pragma unroll
    for (int i = 0; i < 4; ++i) {
        int idx = t + 128 * i;          // float4 idx 0..511
        int row = idx >> 3, k4 = idx & 7;
        float4 v = ((const float4*)h)[rowBase * 8 + idx];
        ((float4*)xs)[row * 8 + ((k4 + (row >> 2)) & 7)] = v;
    }
    __syncthreads();

    const int cg = t & 7;
    const int rg = t >> 3;
    const float4* xs4  = (const float4*)xs;
    const float4* wls4 = (const float4*)wls;
    const float4* wrs4 = (const float4*)wrs;

    float4 accY[4], accZ[4];
#pragma unroll
    for (int i = 0; i < 4; ++i) {
        accY[i] = make_float4(0.f, 0.f, 0.f, 0.f);
        accZ[i] = make_float4(0.f, 0.f, 0.f, 0.f);
    }

#pragma unroll
    for (int k4 = 0; k4 < 8; ++k4) {
        float4 xv[4];
#pragma unroll
        for (int i = 0; i < 4; ++i)
            xv[i] = xs4[(4 * rg + i) * 8 + ((k4 + rg) & 7)];
        const int kb = 4 * k4;
        float4 w0 = wls4[(kb + 0) * 8 + ((cg + kb + 0) & 7)];
        float4 w1 = wls4[(kb + 1) * 8 + ((cg + kb + 1) & 7)];
        float4 w2 = wls4[(kb + 2) * 8 + ((cg + kb + 2) & 7)];
        float4 w3 = wls4[(kb + 3) * 8 + ((cg + kb + 3) & 7)];
#pragma unroll
        for (int i = 0; i < 4; ++i) {
            fma4(accY[i], xv[i].x, w0);
            fma4(accY[i], xv[i].y, w1);
            fma4(accY[i], xv[i].z, w2);
            fma4(accY[i], xv[i].w, w3);
        }
        if (doZ) {
            float4 u0 = wrs4[(kb + 0) * 8 + ((cg + kb + 0) & 7)];
            float4 u1 = wrs4[(kb + 1) * 8 + ((cg + kb + 1) & 7)];
            float4 u2 = wrs4[(kb + 2) * 8 + ((cg + kb + 2) & 7)];
            float4 u3 = wrs4[(kb + 3) * 8 + ((cg + kb + 3) & 7)];
#pragma unroll
            for (int i = 0; i < 4; ++i) {
                fma4(accZ[i], xv[i].x, u0);
                fma4(accZ[i], xv[i].y, u1);
                fma4(accZ[i], xv[i].z, u2);
                fma4(accZ[i], xv[i].w, u3);
            }
        }
    }
#pragma unroll
    for (int i = 0; i < 4; ++i) {
        long r = rowBase + 4 * rg + i;
        ((float4*)y)[r * 8 + cg] = accY[i];
        if (doZ) ((float4*)z)[r * 8 + cg] = accZ[i];
    }
}

// ---------------- CSR build: per-target histogram ----------------
__global__ __launch_bounds__(256) void hist_kernel(
    const int* __restrict__ tgt, int* __restrict__ cnt, int nE)
{
    int e = blockIdx.x * 256 + threadIdx.x;
    if (e < nE) atomicAdd(&cnt[tgt[e]], 1);
}

// ---------------- CSR build: 2-level exclusive scan ----------------
__global__ __launch_bounds__(256) void scanA_kernel(
    const int* __restrict__ cnt, int* __restrict__ cursor, int* __restrict__ bsum)
{
    __shared__ int s[256];
    int t = threadIdx.x;
    int base = blockIdx.x * 512;
    int c0 = cnt[base + 2 * t];
    int c1 = cnt[base + 2 * t + 1];
    int local = c0 + c1;
    s[t] = local;
    __syncthreads();
    int v = local;
#pragma unroll
    for (int off = 1; off < 256; off <<= 1) {
        int u = (t >= off) ? s[t - off] : 0;
        __syncthreads();
        v += u;
        s[t] = v;
        __syncthreads();
    }
    int ex = v - local;
    cursor[base + 2 * t]     = ex;
    cursor[base + 2 * t + 1] = ex + c0;
    if (t == 255) bsum[blockIdx.x] = v;
}

__global__ __launch_bounds__(256) void scanB_kernel(int* __restrict__ bsum, int nb)
{
    __shared__ int s[256];
    int t = threadIdx.x;
    int local = (t < nb) ? bsum[t] : 0;
    s[t] = local;
    __syncthreads();
    int v = local;
#pragma unroll
    for (int off = 1; off < 256; off <<= 1) {
        int u = (t >= off) ? s[t - off] : 0;
        __syncthreads();
        v += u;
        s[t] = v;
        __syncthreads();
    }
    if (t < nb) bsum[t] = v - local;
}

// scanC: add block offsets; also emit per-bucket (512-target group) base cursors
__global__ __launch_bounds__(256) void scanC_kernel(
    int* __restrict__ cursor, const int* __restrict__ bsum, int* __restrict__ bcur)
{
    int i = blockIdx.x * 256 + threadIdx.x;
    int v = cursor[i] + bsum[i >> 9];
    cursor[i] = v;
    if ((i & 511) == 0) bcur[i >> 9] = v;
}

// ---------------- partition pass 1: multisplit into 512-target buckets ----------------
// Each block owns 8192 edges. LDS histogram -> one global atomic per bucket ->
// write (src,tgt) pairs into block-reserved contiguous chunks.
__global__ __launch_bounds__(256) void part_kernel(
    const int* __restrict__ src, const int* __restrict__ tgt,
    int2* __restrict__ pairs, int* __restrict__ bcur, int nb)
{
    __shared__ int hist[256];
    __shared__ int bbase[256];
    const int t = threadIdx.x;
    const int base = blockIdx.x * 8192;
    hist[t] = 0;
    __syncthreads();
#pragma unroll 4
    for (int i = 0; i < 32; ++i) {
        int e = base + i * 256 + t;
        atomicAdd(&hist[tgt[e] >> 9], 1);
    }
    __syncthreads();
    if (t < nb) bbase[t] = atomicAdd(&bcur[t], hist[t]);
    __syncthreads();
    hist[t] = 0;
    __syncthreads();
#pragma unroll 4
    for (int i = 0; i < 32; ++i) {
        int e = base + i * 256 + t;
        int tv = tgt[e], sv = src[e];
        int b = tv >> 9;
        int r = atomicAdd(&hist[b], 1);
        pairs[bbase[b] + r] = make_int2(sv, tv);
    }
}

// ---------------- partition pass 2: bucket-local rank -> eidx ----------------
// One block per bucket; LDS rank counters give pos = cur[tgt] + rank.
// All eidx writes land in this bucket's contiguous region (single-block owned).
__global__ __launch_bounds__(512) void sortb_kernel(
    const int2* __restrict__ pairs, const int* __restrict__ cur,
    int* __restrict__ eidx, int nT, int nE)
{
    __shared__ int lrank[512];
    const int b = blockIdx.x;
    const int t = threadIdx.x;
    lrank[t] = 0;
    __syncthreads();
    const int tlo = b << 9;
    const int beg = cur[tlo];
    const int thi = tlo + 512;
    const int end = (thi < nT) ? cur[thi] : nE;
    for (int e = beg + t; e < end; e += 512) {
        int2 p = pairs[e];
        int r = atomicAdd(&lrank[p.y - tlo], 1);
        eidx[cur[p.y] + r] = p.x;
    }
}

// ---------------- gather-reduce + fused epilogue ----------------
__global__ __launch_bounds__(256) void gather_agg_kernel(
    const float* __restrict__ yv, const int* __restrict__ eidx,
    const int* __restrict__ cnt, const int* __restrict__ cur,
    const float* __restrict__ z, const float* __restrict__ b,
    float* __restrict__ out, int n, int doRelu)
{
    int t = blockIdx.x * 256 + threadIdx.x;
    int row = t >> 3, part = t & 7;
    if (row >= n) return;
    int c = cnt[row];
    int beg = cur[row];
    int end = beg + c;
    const float4* y4 = (const float4*)yv;
    float4 acc = make_float4(0.f, 0.f, 0.f, 0.f);
    int e = beg;
    for (; e + 1 < end; e += 2) {
        int s0 = eidx[e], s1 = eidx[e + 1];
        float4 v0 = y4[(long)s0 * 8 + part];
        float4 v1 = y4[(long)s1 * 8 + part];
        acc.x += v0.x + v1.x;
        acc.y += v0.y + v1.y;
        acc.z += v0.z + v1.z;
        acc.w += v0.w + v1.w;
    }
    if (e < end) {
        int s0 = eidx[e];
        float4 v0 = y4[(long)s0 * 8 + part];
        acc.x += v0.x; acc.y += v0.y; acc.z += v0.z; acc.w += v0.w;
    }
    float inv = 1.f / fmaxf((float)c, 1.f);
    float4 bb = ((const float4*)b)[part];
    float4 zz = ((const float4*)z)[(long)row * 8 + part];
    float4 v;
    v.x = fmaf(acc.x, inv, bb.x) + zz.x;
    v.y = fmaf(acc.y, inv, bb.y) + zz.y;
    v.z = fmaf(acc.z, inv, bb.z) + zz.z;
    v.w = fmaf(acc.w, inv, bb.w) + zz.w;
    float ss = v.x * v.x + v.y * v.y + v.z * v.z + v.w * v.w;
    ss += __shfl_xor(ss, 1);
    ss += __shfl_xor(ss, 2);
    ss += __shfl_xor(ss, 4);
    float q = 1.f / fmaxf(sqrtf(ss), 1e-12f);
    v.x *= q; v.y *= q; v.z *= q; v.w *= q;
    if (doRelu) {
        v.x = fmaxf(v.x, 0.f); v.y = fmaxf(v.y, 0.f);
        v.z = fmaxf(v.z, 0.f); v.w = fmaxf(v.w, 0.f);
    }
    ((float4*)out)[(long)row * 8 + part] = v;
}

extern "C" void kernel_launch(void* const* d_in, const int* in_sizes, int n_in,
                              void* d_out, int out_size, void* d_ws, size_t ws_size,
                              hipStream_t stream) {
    const float* x   = (const float*)d_in[0];
    const int* src0  = (const int*)d_in[1];
    const int* tgt0  = (const int*)d_in[2];
    const int* src1  = (const int*)d_in[3];
    const int* tgt1  = (const int*)d_in[4];
    const float* wl0 = (const float*)d_in[5];
    const float* bl0 = (const float*)d_in[6];
    const float* wr0 = (const float*)d_in[7];
    const float* wl1 = (const float*)d_in[8];
    const float* bl1 = (const float*)d_in[9];
    const float* wr1 = (const float*)d_in[10];

    char* W = (char*)d_ws;
    // region A [0,32M): y0; after gather0 reused for layer-1 buffers
    float* y0    = (float*)(W + 0);             // 32 MB
    float* y1    = (float*)(W + 0);             // 16 MB
    float* z1    = (float*)(W + 16777216);      //  8 MB
    int*   eidx1 = (int*)  (W + 25165824);      //  4 MB
    int*   cnt1  = (int*)  (W + 29360128);      // 256 KB
    int*   cur1  = (int*)  (W + 29622272);      // 256 KB
    // region B [32M,48M): z0; after gather0 reused for pairs1 (8 MB)
    float* z0    = (float*)(W + 33554432);      // 16 MB
    int2*  pairs1= (int2*) (W + 33554432);      //  8 MB
    // region C [48M,64M): pairs0 (live P1->P2), then h (written by gather0 after P2)
    int2*  pairs0= (int2*) (W + 50331648);      // 16 MB
    float* h     = (float*)(W + 50331648);      // 16 MB
    // region D [64M,72M): eidx0
    int*   eidx0 = (int*)  (W + 67108864);      //  8 MB
    // region E [72M,...): cnt0, cur0, bsum, bcur
    int*   cnt0  = (int*)  (W + 75497472);      // 512 KB
    int*   cur0  = (int*)  (W + 76021760);      // 512 KB
    int*   bsum  = (int*)  (W + 76546048);      //  1 KB
    int*   bcur  = (int*)  (W + 76547072);      //  1 KB

    // ---- layer 0 ----
    hipMemsetAsync(cnt0, 0, 524288, stream);
    lin0_kernel<<<N0c / 64, 128, 0, stream>>>(x, wl0, wr0, y0, z0);
    hist_kernel<<<E0c / 256, 256, 0, stream>>>(tgt0, cnt0, E0c);
    scanA_kernel<<<N1c / 512, 256, 0, stream>>>(cnt0, cur0, bsum);
    scanB_kernel<<<1, 256, 0, stream>>>(bsum, N1c / 512);
    scanC_kernel<<<N1c / 256, 256, 0, stream>>>(cur0, bsum, bcur);
    part_kernel<<<E0c / 8192, 256, 0, stream>>>(src0, tgt0, pairs0, bcur, 256);
    sortb_kernel<<<N1c / 512, 512, 0, stream>>>(pairs0, cur0, eidx0, N1c, E0c);
    gather_agg_kernel<<<(N1c * 8) / 256, 256, 0, stream>>>(y0, eidx0, cnt0, cur0,
                                                           z0, bl0, h, N1c, 1);

    // ---- layer 1 (y0/z0 dead; regions A/B reused) ----
    hipMemsetAsync(cnt1, 0, 262144, stream);
    hist_kernel<<<E1c / 256, 256, 0, stream>>>(tgt1, cnt1, E1c);
    scanA_kernel<<<N2c / 512, 256, 0, stream>>>(cnt1, cur1, bsum);
    scanB_kernel<<<1, 256, 0, stream>>>(bsum, N2c / 512);
    scanC_kernel<<<N2c / 256, 256, 0, stream>>>(cur1, bsum, bcur);
    part_kernel<<<E1c / 8192, 256, 0, stream>>>(src1, tgt1, pairs1, bcur, 128);
    lin1_kernel<<<N1c / 64, 128, 0, stream>>>(h, wl1, wr1, y1, z1);
    sortb_kernel<<<N2c / 512, 512, 0, stream>>>(pairs1, cur1, eidx1, N2c, E1c);
    gather_agg_kernel<<<(N2c * 8) / 256, 256, 0, stream>>>(y1, eidx1, cnt1, cur1,
                                                           z1, bl1, (float*)d_out, N2c, 0);
}